// Round 2
// baseline (28.123 us; speedup 1.0000x reference)
//
#include <hip/hip_runtime.h>

// Problem constants from setup_inputs(): mixing (K=16, B=32, 1, W=256, H=256) f32.
#define K_ 16
#define B_ 32
#define W_ 256
#define H_ 256
#define KB_ (K_ * B_)
#define CHUNK_ (W_ * H_)   // 65536 elements per (k,b) slice

// One block per (k,b). 1024 threads, each reads 16 float4 (64 elems).
// Structure exploited: for thread t at iteration it,
//   element index = (it*1024 + t)*4
//   h  = (4t) & 255            -- constant across iterations
//   w  = 16*it + (t>>6)        -- strictly increasing in it
// So instead of 4 masked maxima per iteration we need only:
//   - running per-element max e0..e3 (gives hi/lo h-offset at the end)
//   - first/last iteration with any element > 0.5 (gives w extents)
// All branch-free; loads issued in two batches of 8 for MLP.
__global__ __launch_bounds__(1024) void box_from_mask_kernel(
    const float* __restrict__ mixing,
    const int* __restrict__ p_pad,
    const int* __restrict__ p_minb,
    const int* __restrict__ p_maxb,
    float* __restrict__ out)
{
    const int kb = blockIdx.x;        // k*B + b
    const int t  = threadIdx.x;       // 0..1023
    const float4* base = reinterpret_cast<const float4*>(mixing + (size_t)kb * CHUNK_);

    float e0 = 0.f, e1 = 0.f, e2 = 0.f, e3 = 0.f;
    int firstIt = 16;   // min it with any hit (sentinel 16)
    int lastIt  = -1;   // max it with any hit

#pragma unroll
    for (int half = 0; half < 2; ++half) {
        float4 v[8];
#pragma unroll
        for (int j = 0; j < 8; ++j) {
            v[j] = base[(half * 8 + j) * 1024 + t];   // 8 loads in flight
        }
#pragma unroll
        for (int j = 0; j < 8; ++j) {
            const int it = half * 8 + j;
            e0 = fmaxf(e0, v[j].x);
            e1 = fmaxf(e1, v[j].y);
            e2 = fmaxf(e2, v[j].z);
            e3 = fmaxf(e3, v[j].w);
            const float am = fmaxf(fmaxf(v[j].x, v[j].y), fmaxf(v[j].z, v[j].w));
            const bool any = am > 0.5f;
            lastIt  = any ? it : lastIt;
            firstIt = min(firstIt, any ? it : 16);
        }
    }

    // Per-thread epilogue: reconstruct the four masked maxima.
    const bool b0 = e0 > 0.5f, b1 = e1 > 0.5f, b2 = e2 > 0.5f, b3 = e3 > 0.5f;
    const bool anyHit = b0 | b1 | b2 | b3;              // == (lastIt >= 0)
    const int hi = b3 ? 3 : (b2 ? 2 : (b1 ? 1 : 0));
    const int lo = b0 ? 0 : (b1 ? 1 : (b2 ? 2 : 3));
    const int h    = (t * 4) & (H_ - 1);
    const int wcol = t >> 6;

    int mh  = anyHit ? h + hi : 0;                       // max h over mask
    int mHh = anyHit ? H_ - (h + lo) : 0;                // max (H-h)
    int mw  = (lastIt >= 0) ? lastIt * 16 + wcol : 0;    // max w
    int mWw = (firstIt < 16) ? W_ - (firstIt * 16 + wcol) : 0; // max (W-w)

    // 64-lane wave reduction (wave = 64 on gfx950)
#pragma unroll
    for (int off = 32; off > 0; off >>= 1) {
        mw  = max(mw,  __shfl_xor(mw,  off));
        mWw = max(mWw, __shfl_xor(mWw, off));
        mh  = max(mh,  __shfl_xor(mh,  off));
        mHh = max(mHh, __shfl_xor(mHh, off));
    }

    __shared__ int s[4][16];   // 16 waves per block
    const int wave = t >> 6;
    const int lane = t & 63;
    if (lane == 0) {
        s[0][wave] = mw; s[1][wave] = mWw; s[2][wave] = mh; s[3][wave] = mHh;
    }
    __syncthreads();

    if (t == 0) {
        int a = 0, b = 0, c = 0, d = 0;
#pragma unroll
        for (int i = 0; i < 16; ++i) {
            a = max(a, s[0][i]);
            b = max(b, s[1][i]);
            c = max(c, s[2][i]);
            d = max(d, s[3][i]);
        }
        const float pad  = (float)(*p_pad);
        const float minb = (float)(*p_minb);
        const float maxb = (float)(*p_maxb);
        const float Wf = (float)W_, Hf = (float)H_;

        // ideal_x3 = a ; ideal_x1 = W - b ; ideal_y3 = c ; ideal_y1 = H - d
        const float x3 = fminf(fmaxf((float)a + pad,        0.0f), Wf);
        const float x1 = fminf(fmaxf((Wf - (float)b) - pad, 0.0f), Wf);
        const float y3 = fminf(fmaxf((float)c + pad,        0.0f), Hf);
        const float y1 = fminf(fmaxf((Hf - (float)d) - pad, 0.0f), Hf);

        out[0 * KB_ + kb] = 0.5f * (x1 + x3);
        out[1 * KB_ + kb] = 0.5f * (y1 + y3);
        out[2 * KB_ + kb] = fminf(fmaxf(x3 - x1, minb), maxb);
        out[3 * KB_ + kb] = fminf(fmaxf(y3 - y1, minb), maxb);
    }
}

extern "C" void kernel_launch(void* const* d_in, const int* in_sizes, int n_in,
                              void* d_out, int out_size, void* d_ws, size_t ws_size,
                              hipStream_t stream) {
    const float* mixing = (const float*)d_in[0];
    const int*   p_pad  = (const int*)d_in[1];
    const int*   p_minb = (const int*)d_in[2];
    const int*   p_maxb = (const int*)d_in[3];
    float* out = (float*)d_out;

    box_from_mask_kernel<<<dim3(KB_), dim3(1024), 0, stream>>>(
        mixing, p_pad, p_minb, p_maxb, out);
}

// Round 3
// 26.835 us; speedup vs baseline: 1.0480x; 1.0480x over previous
//
#include <hip/hip_runtime.h>

// Problem constants from setup_inputs(): mixing (K=16, B=32, 1, W=256, H=256) f32.
#define K_ 16
#define B_ 32
#define W_ 256
#define H_ 256
#define KB_ (K_ * B_)
#define CHUNK_ (W_ * H_)   // 65536 elements per (k,b) slice

// One block per (k,b). 1024 threads, each reads 16 float4 (64 elems).
// Structure exploited: for thread t at iteration it,
//   element index = (it*1024 + t)*4
//   h  = (4t) & 255            -- constant across iterations
//   w  = 16*it + (t>>6)        -- strictly increasing in it
// So we only need: per-element running max e0..e3 (h extents at the end) and
// first/last iteration with any hit (w extents).
//
// __launch_bounds__(1024, 8): 8 waves/EU min -> forces VGPR <= 64 so TWO
// 1024-thread blocks co-reside per CU (32 waves/CU). Load batches of 4
// (16 data VGPRs) keep pressure well under the bound.
__global__ __launch_bounds__(1024, 8) void box_from_mask_kernel(
    const float* __restrict__ mixing,
    const int* __restrict__ p_pad,
    const int* __restrict__ p_minb,
    const int* __restrict__ p_maxb,
    float* __restrict__ out)
{
    const int kb = blockIdx.x;        // k*B + b
    const int t  = threadIdx.x;       // 0..1023
    const float4* base = reinterpret_cast<const float4*>(mixing + (size_t)kb * CHUNK_);

    float e0 = 0.f, e1 = 0.f, e2 = 0.f, e3 = 0.f;
    int firstIt = 16;   // min it with any hit (sentinel 16)
    int lastIt  = -1;   // max it with any hit

#pragma unroll
    for (int q = 0; q < 4; ++q) {
        float4 v[4];
#pragma unroll
        for (int j = 0; j < 4; ++j) {
            v[j] = base[(q * 4 + j) * 1024 + t];   // 4 loads in flight
        }
#pragma unroll
        for (int j = 0; j < 4; ++j) {
            const int it = q * 4 + j;
            e0 = fmaxf(e0, v[j].x);
            e1 = fmaxf(e1, v[j].y);
            e2 = fmaxf(e2, v[j].z);
            e3 = fmaxf(e3, v[j].w);
            const float am = fmaxf(fmaxf(v[j].x, v[j].y), fmaxf(v[j].z, v[j].w));
            const bool any = am > 0.5f;
            lastIt  = any ? it : lastIt;
            firstIt = min(firstIt, any ? it : 16);
        }
    }

    // Per-thread epilogue: reconstruct the four masked maxima.
    const bool b0 = e0 > 0.5f, b1 = e1 > 0.5f, b2 = e2 > 0.5f, b3 = e3 > 0.5f;
    const bool anyHit = b0 | b1 | b2 | b3;              // == (lastIt >= 0)
    const int hi = b3 ? 3 : (b2 ? 2 : (b1 ? 1 : 0));
    const int lo = b0 ? 0 : (b1 ? 1 : (b2 ? 2 : 3));
    const int h    = (t * 4) & (H_ - 1);
    const int wcol = t >> 6;

    int mh  = anyHit ? h + hi : 0;                       // max h over mask
    int mHh = anyHit ? H_ - (h + lo) : 0;                // max (H-h)
    int mw  = (lastIt >= 0) ? lastIt * 16 + wcol : 0;    // max w
    int mWw = (firstIt < 16) ? W_ - (firstIt * 16 + wcol) : 0; // max (W-w)

    // 64-lane wave reduction (wave = 64 on gfx950)
#pragma unroll
    for (int off = 32; off > 0; off >>= 1) {
        mw  = max(mw,  __shfl_xor(mw,  off));
        mWw = max(mWw, __shfl_xor(mWw, off));
        mh  = max(mh,  __shfl_xor(mh,  off));
        mHh = max(mHh, __shfl_xor(mHh, off));
    }

    __shared__ int s[4][16];   // 16 waves per block
    const int wave = t >> 6;
    const int lane = t & 63;
    if (lane == 0) {
        s[0][wave] = mw; s[1][wave] = mWw; s[2][wave] = mh; s[3][wave] = mHh;
    }
    __syncthreads();

    if (t == 0) {
        int a = 0, b = 0, c = 0, d = 0;
#pragma unroll
        for (int i = 0; i < 16; ++i) {
            a = max(a, s[0][i]);
            b = max(b, s[1][i]);
            c = max(c, s[2][i]);
            d = max(d, s[3][i]);
        }
        const float pad  = (float)(*p_pad);
        const float minb = (float)(*p_minb);
        const float maxb = (float)(*p_maxb);
        const float Wf = (float)W_, Hf = (float)H_;

        // ideal_x3 = a ; ideal_x1 = W - b ; ideal_y3 = c ; ideal_y1 = H - d
        const float x3 = fminf(fmaxf((float)a + pad,        0.0f), Wf);
        const float x1 = fminf(fmaxf((Wf - (float)b) - pad, 0.0f), Wf);
        const float y3 = fminf(fmaxf((float)c + pad,        0.0f), Hf);
        const float y1 = fminf(fmaxf((Hf - (float)d) - pad, 0.0f), Hf);

        out[0 * KB_ + kb] = 0.5f * (x1 + x3);
        out[1 * KB_ + kb] = 0.5f * (y1 + y3);
        out[2 * KB_ + kb] = fminf(fmaxf(x3 - x1, minb), maxb);
        out[3 * KB_ + kb] = fminf(fmaxf(y3 - y1, minb), maxb);
    }
}

extern "C" void kernel_launch(void* const* d_in, const int* in_sizes, int n_in,
                              void* d_out, int out_size, void* d_ws, size_t ws_size,
                              hipStream_t stream) {
    const float* mixing = (const float*)d_in[0];
    const int*   p_pad  = (const int*)d_in[1];
    const int*   p_minb = (const int*)d_in[2];
    const int*   p_maxb = (const int*)d_in[3];
    float* out = (float*)d_out;

    box_from_mask_kernel<<<dim3(KB_), dim3(1024), 0, stream>>>(
        mixing, p_pad, p_minb, p_maxb, out);
}